// Round 5
// baseline (21360.651 us; speedup 1.0000x reference)
//
#include <hip/hip_runtime.h>
#include <cstdint>
#include <cstddef>

typedef unsigned short u16;
typedef unsigned int u32;
typedef unsigned long long u64;
typedef __attribute__((ext_vector_type(8))) short bf16x8;  // 8 bf16 (4 VGPRs) — MFMA A/B frag
typedef __attribute__((ext_vector_type(4))) float f32x4;   // MFMA C/D frag

#define T_SEQ 512
#define HID 512

// ---------- dtype helpers ----------
__device__ __forceinline__ u16 f2bf(float f) {
  union { float f; u32 i; } c; c.f = f;
  u32 r = (c.i + 0x7FFFu + ((c.i >> 16) & 1u)) >> 16;  // RNE
  return (u16)r;
}
__device__ __forceinline__ u16 f2h(float f) {
  union { _Float16 h; u16 u; } c; c.h = (_Float16)f; return c.u;
}
__device__ __forceinline__ float h2f(u16 u) {
  union { u16 u; _Float16 h; } c; c.u = u; return (float)c.h;
}
__device__ __forceinline__ float sigmf(float x) { return 1.f / (1.f + __expf(-x)); }
__device__ __forceinline__ float tanhfast(float x) {
  float e = __expf(2.f * x); return 1.f - 2.f / (e + 1.f);  // saturates to ±1
}
__device__ __forceinline__ bf16x8 pack8(const float* p) {
  float4 a = *(const float4*)(p);
  float4 b = *(const float4*)(p + 4);
  bf16x8 fr;
  fr[0] = (short)f2bf(a.x); fr[1] = (short)f2bf(a.y);
  fr[2] = (short)f2bf(a.z); fr[3] = (short)f2bf(a.w);
  fr[4] = (short)f2bf(b.x); fr[5] = (short)f2bf(b.y);
  fr[6] = (short)f2bf(b.z); fr[7] = (short)f2bf(b.w);
  return fr;
}

// ---------------------------------------------------------------------------
// xg GEMM: xg[dir][m][n] = sum_k A[m][k] * W[dir][n][k] + bias[dir][n]
// A: [8192, K] (fp32 if AF32 else bf16) row-major; W: [1536, K] fp32 row-major.
// out: fp16 [8192,1536]. 128x128 tile, BK=32, 4 waves (2x2), 4x4 16x16x32 MFMA.
// (unchanged — not the bottleneck)
// ---------------------------------------------------------------------------
template <int AF32>
__launch_bounds__(256)
__global__ void gemm_xg(const void* __restrict__ Av,
                        const float* __restrict__ W0, const float* __restrict__ W1,
                        const float* __restrict__ b0, const float* __restrict__ b1,
                        u16* __restrict__ xg0, u16* __restrict__ xg1, int K) {
  const int dir = blockIdx.z;
  const float* W = dir ? W1 : W0;
  const float* bias = dir ? b1 : b0;
  u16* xg = dir ? xg1 : xg0;
  const int bm = blockIdx.x, bn = blockIdx.y;
  const int tid = threadIdx.x, lane = tid & 63, wv = tid >> 6;
  const int wm = wv & 1, wn = wv >> 1, quad = lane >> 4, l15 = lane & 15;

  __shared__ u16 As[128 * 40];  // +8 pad per 32-elem row -> conflict-free b128 reads
  __shared__ u16 Bs[128 * 40];

  f32x4 acc[4][4] = {};
  const float* Wb = W + (size_t)(bn * 128) * K;

  for (int k0 = 0; k0 < K; k0 += 32) {
    __syncthreads();  // protect LDS from previous iter's readers
    if constexpr (AF32) {
      const float* Ab = (const float*)Av + (size_t)(bm * 128) * K;
#pragma unroll
      for (int it = 0; it < 4; ++it) {
        int c = tid + it * 256;  // 1024 float4 chunks
        int row = c >> 3, kp = (c & 7) * 4;
        float4 v = *(const float4*)(Ab + (size_t)row * K + k0 + kp);
        ushort4 s = { f2bf(v.x), f2bf(v.y), f2bf(v.z), f2bf(v.w) };
        *(ushort4*)(&As[row * 40 + kp]) = s;
      }
    } else {
      const u16* Ab = (const u16*)Av + (size_t)(bm * 128) * K;
#pragma unroll
      for (int it = 0; it < 2; ++it) {
        int c = tid + it * 256;  // 512 chunks of 8 bf16
        int row = c >> 2, kp = (c & 3) * 8;
        *(bf16x8*)(&As[row * 40 + kp]) = *(const bf16x8*)(Ab + (size_t)row * K + k0 + kp);
      }
    }
#pragma unroll
    for (int it = 0; it < 4; ++it) {  // W is always fp32
      int c = tid + it * 256;
      int row = c >> 3, kp = (c & 7) * 4;
      float4 v = *(const float4*)(Wb + (size_t)row * K + k0 + kp);
      ushort4 s = { f2bf(v.x), f2bf(v.y), f2bf(v.z), f2bf(v.w) };
      *(ushort4*)(&Bs[row * 40 + kp]) = s;
    }
    __syncthreads();
    bf16x8 af[4], bfv[4];
#pragma unroll
    for (int i = 0; i < 4; ++i) {
      af[i] = *(const bf16x8*)(&As[(wm * 64 + i * 16 + l15) * 40 + quad * 8]);
      bfv[i] = *(const bf16x8*)(&Bs[(wn * 64 + i * 16 + l15) * 40 + quad * 8]);
    }
#pragma unroll
    for (int mi = 0; mi < 4; ++mi)
#pragma unroll
      for (int ni = 0; ni < 4; ++ni)
        acc[mi][ni] = __builtin_amdgcn_mfma_f32_16x16x32_bf16(af[mi], bfv[ni], acc[mi][ni], 0, 0, 0);
  }

  // epilogue: + bias, store fp16
#pragma unroll
  for (int ni = 0; ni < 4; ++ni) {
    int n = bn * 128 + wn * 64 + ni * 16 + l15;
    float bv = bias[n];
#pragma unroll
    for (int mi = 0; mi < 4; ++mi) {
      int m0 = bm * 128 + wm * 64 + mi * 16 + quad * 4;
#pragma unroll
      for (int r = 0; r < 4; ++r)
        xg[(size_t)(m0 + r) * 1536 + n] = f2h(acc[mi][ni][r] + bv);
    }
  }
}

// ---------------------------------------------------------------------------
// Persistent GRU recurrence, v5: ZERO fences, ZERO barriers in the step loop.
// Post-mortem v1..v4: per-step cost pinned at ~6µs by serialized agent-scope
// coherence events — most of all the acquire fence (buffer_inv = full L1+L2
// invalidate, once per WG per step, present in every prior version) plus the
// barrier rallies coupling 8 waves to the slowest.
// v5 removes the machinery instead of rearranging it:
//  * h is READ with agent-scope RELAXED ATOMIC b64 loads — served directly at
//    the LLC coherence point. No plain load ever touches hbuf, so L1/L2 never
//    hold hbuf lines and NO ACQUIRE FENCE is needed, ever.
//  * hand-rolled per-wave release: relaxed-atomic h publish (write-through to
//    LLC) -> inline s_waitcnt vmcnt(0) (own stores acked at LLC) -> relaxed
//    per-wave flag store. No buffer_wbl2, no RMW, no pre-release barrier.
//  * every wave polls the 32 per-wave flags itself (128B-spaced lines) and is
//    fully self-timed — no __syncthreads anywhere in the loop.
// Safety: flag[wv]=t+2 implies that wave's step-t loads AND stores retired
// (vmcnt covers both), so when all flags >= t+1 nobody still needs parity
// (t-2)&1 and writing parity t&1 is safe (skew bounded to 1 step). Flags are
// monotone -> deadlock-free by induction. Lane-local gate math unchanged
// (zero LDS bank conflicts, verified v2-v4).
// ---------------------------------------------------------------------------
__launch_bounds__(512, 2)
__global__ void gru_rec(const u16* __restrict__ xg_f, const u16* __restrict__ xg_b,
                        const float* __restrict__ whh_f, const float* __restrict__ whh_b,
                        const float* __restrict__ bhh_f, const float* __restrict__ bhh_b,
                        const float* __restrict__ h0_f, const float* __restrict__ h0_b,
                        void* __restrict__ outp, int out_stride, int out_f32,
                        u16* __restrict__ hbuf, int* __restrict__ counters, int Tn) {
  const int dir = blockIdx.y;
  const u16* xg   = dir ? xg_b  : xg_f;
  const float* whh = dir ? whh_b : whh_f;
  const float* bhh = dir ? bhh_b : bhh_f;
  const float* h0  = dir ? h0_b  : h0_f;
  const int w = blockIdx.x;                      // 0..3
  const int tid = threadIdx.x, lane = tid & 63, wv = tid >> 6;  // wv 0..7
  const int quad = lane >> 4, l15 = lane & 15;
  const int gcol = w * 128 + wv * 16 + l15;      // hidden unit this lane owns
  int* flg = counters + dir * 1024;              // 32 flags, 32-int (128B) spaced
  const int myflag = (w * 8 + wv) * 32;
  u16* hb0 = hbuf + (dir * 2 + 0) * (16 * 512);
  u16* hb1 = hbuf + (dir * 2 + 1) * (16 * 512);
  const int dir_off = dir * 512;

  __shared__ u16 nlds[8 * 8192];                 // 128 KB: per-wave n-gate whh frags

  // --- whh B-frags: rows g*512+gcol, k = kt*32 + quad*8 + j (HW layout m89/m120) ---
  bf16x8 bfr[2][16];
  {
    const float* wr = whh + (size_t)(0 * 512 + gcol) * 512 + quad * 8;
    const float* wz = whh + (size_t)(1 * 512 + gcol) * 512 + quad * 8;
    const float* wn = whh + (size_t)(2 * 512 + gcol) * 512 + quad * 8;
#pragma unroll
    for (int kt = 0; kt < 16; ++kt) {
      bfr[0][kt] = pack8(wr + kt * 32);
      bfr[1][kt] = pack8(wz + kt * 32);
      *(bf16x8*)(&nlds[wv * 8192 + kt * 512 + lane * 8]) = pack8(wn + kt * 32);  // wave-private
    }
  }
  const float bh0 = bhh[0 * 512 + gcol];
  const float bh1 = bhh[1 * 512 + gcol];
  const float bh2 = bhh[2 * 512 + gcol];

  // --- init h: fp32 regs (exact carry) + publish bf16 h0 slice to hb1 ---
  float hv[4];
#pragma unroll
  for (int r = 0; r < 4; ++r) hv[r] = h0[(quad * 4 + r) * 512 + gcol];
#pragma unroll
  for (int r = 0; r < 4; ++r) {
    u32 hb = (u32)f2bf(hv[r]);
    u32 pb = (u32)__shfl_xor((int)hb, 1, 64);
    if (!(lane & 1))
      __hip_atomic_store((u32*)(hb1 + (quad * 4 + r) * 512 + gcol), hb | (pb << 16),
                         __ATOMIC_RELAXED, __HIP_MEMORY_SCOPE_AGENT);
  }
  asm volatile("s_waitcnt vmcnt(0)" ::: "memory");  // own h0 stores acked at LLC
  if (lane == 0)
    __hip_atomic_store(&flg[myflag], 1, __ATOMIC_RELAXED, __HIP_MEMORY_SCOPE_AGENT);

  for (int t = 0; t < Tn; ++t) {
    const int te = dir ? (Tn - 1 - t) : t;

    // (a) xg slice for this lane's 4 batch rows -> 12 regs (completes under poll)
    u16 xv[12];
    {
      const u16* xb = xg + (size_t)te * 1536 + gcol;
#pragma unroll
      for (int r = 0; r < 4; ++r)
#pragma unroll
        for (int g = 0; g < 3; ++g)
          xv[r * 3 + g] = xb[(size_t)(quad * 4 + r) * Tn * 1536 + g * 512];
    }

    // (b) self-timed: this wave polls all 32 producer flags (no fence, no barrier)
    {
      const int target = t + 1;
      while (1) {
        int v = (lane < 32)
            ? __hip_atomic_load(&flg[lane * 32], __ATOMIC_RELAXED, __HIP_MEMORY_SCOPE_AGENT)
            : 0x7fffffff;
        if (__all(v >= target)) break;
        __builtin_amdgcn_s_sleep(1);
      }
    }

    // (c) A-frags: full 16x512 bf16 h via LLC-direct relaxed-atomic b64 loads.
    //     Correct without a fence: hbuf lines never enter L1/L2 (no plain
    //     access anywhere), and producers' stores were vmcnt-acked at the LLC
    //     before their flag stores.
    const u64* hq = (const u64*)(((t & 1) ? hb0 : hb1) + l15 * 512 + quad * 8);
    bf16x8 afr[16];
#pragma unroll
    for (int kt = 0; kt < 16; ++kt) {
      u64 lo = __hip_atomic_load(hq + kt * 8,     __ATOMIC_RELAXED, __HIP_MEMORY_SCOPE_AGENT);
      u64 hi = __hip_atomic_load(hq + kt * 8 + 1, __ATOMIC_RELAXED, __HIP_MEMORY_SCOPE_AGENT);
      union { bf16x8 v; u64 q[2]; } uu;
      uu.q[0] = lo; uu.q[1] = hi;
      afr[kt] = uu.v;
    }

    // (d) MFMA: three independent 16-deep chains (r,z from regs; n from LDS)
    f32x4 accr = {0.f, 0.f, 0.f, 0.f}, accz = accr, accn = accr;
#pragma unroll
    for (int kt = 0; kt < 16; ++kt) {
      bf16x8 nf = *(const bf16x8*)(&nlds[wv * 8192 + kt * 512 + lane * 8]);
      accr = __builtin_amdgcn_mfma_f32_16x16x32_bf16(afr[kt], bfr[0][kt], accr, 0, 0, 0);
      accz = __builtin_amdgcn_mfma_f32_16x16x32_bf16(afr[kt], bfr[1][kt], accz, 0, 0, 0);
      accn = __builtin_amdgcn_mfma_f32_16x16x32_bf16(afr[kt], nf, accn, 0, 0, 0);
    }

    // (e) lane-local gate combine + fp32 h update
#pragma unroll
    for (int r = 0; r < 4; ++r) {
      float xr = h2f(xv[r * 3 + 0]);
      float xz = h2f(xv[r * 3 + 1]);
      float xn = h2f(xv[r * 3 + 2]);
      float rg = sigmf(xr + accr[r] + bh0);
      float zg = sigmf(xz + accz[r] + bh1);
      float ng = tanhfast(xn + rg * (accn[r] + bh2));
      hv[r] = (1.f - zg) * ng + zg * hv[r];
    }

    // (f) publish bf16 h (packed pairs via shfl; write-through agent stores),
    //     then hand-rolled per-wave release: vmcnt(0) drain + relaxed flag.
    u16* hbw = (t & 1) ? hb1 : hb0;
    u32 opk[4];
#pragma unroll
    for (int r = 0; r < 4; ++r) {
      u32 hb = (u32)f2bf(hv[r]);
      u32 pb = (u32)__shfl_xor((int)hb, 1, 64);
      opk[r] = hb | (pb << 16);
      if (!(lane & 1))
        __hip_atomic_store((u32*)(hbw + (quad * 4 + r) * 512 + gcol), opk[r],
                           __ATOMIC_RELAXED, __HIP_MEMORY_SCOPE_AGENT);
    }
    asm volatile("s_waitcnt vmcnt(0)" ::: "memory");  // h stores acked at LLC
    if (lane == 0)
      __hip_atomic_store(&flg[myflag], t + 2, __ATOMIC_RELAXED, __HIP_MEMORY_SCOPE_AGENT);

    // (h) sequence output — plain stores AFTER the flag (off the critical
    //     path; end-of-kernel release flushes L2 for the next dispatch)
    if (out_f32) {
#pragma unroll
      for (int r = 0; r < 4; ++r) {
        float pf = __shfl_xor(hv[r], 1, 64);
        if (!(lane & 1)) {
          float2 o = { hv[r], pf };
          *(float2*)((float*)outp + (size_t)((quad * 4 + r) * Tn + te) * out_stride + dir_off + gcol) = o;
        }
      }
    } else {
#pragma unroll
      for (int r = 0; r < 4; ++r)
        if (!(lane & 1))
          *(u32*)((u16*)outp + (size_t)((quad * 4 + r) * Tn + te) * out_stride + dir_off + gcol) = opk[r];
    }
  }
}

// ---------------------------------------------------------------------------
// Final FC: d_out[b] = sigmoid(out2[b, T-1, :] . fc_w + fc_b)   (all fp32)
// ---------------------------------------------------------------------------
__global__ void fc_kernel(const float* __restrict__ out2, const float* __restrict__ fc_w,
                          const float* __restrict__ fc_b, float* __restrict__ dst) {
  int b = blockIdx.x, lane = threadIdx.x;  // 64 threads
  const float* row = out2 + ((size_t)b * T_SEQ + (T_SEQ - 1)) * HID;
  float s = 0.f;
  for (int j = lane; j < HID; j += 64) s += row[j] * fc_w[j];
#pragma unroll
  for (int off = 32; off > 0; off >>= 1) s += __shfl_down(s, off, 64);
  if (lane == 0) dst[b] = sigmf(s + fc_b[0]);
}

// ---------------------------------------------------------------------------
// inputs (fp32): 0 x, 1 h1, 2 h2, [3..6]=l0f(wih,whh,bih,bhh), [7..10]=l0b,
// [11..14]=l1f, [15..18]=l1b, [19..22]=l2f, [23..26]=l2b, [27..30]=g2, 31 fc_w, 32 fc_b
// d_out (fp32): 16 sigmoid logits, then out2 [16,512,512].
// ws: xg0 fp16 (8192*1536) | xg1 fp16 | outb bf16 (8192*1024) | hbuf bf16 (4*8192)
//     | counters (8192 int)
// ---------------------------------------------------------------------------
extern "C" void kernel_launch(void* const* d_in, const int* in_sizes, int n_in,
                              void* d_out, int out_size, void* d_ws, size_t ws_size,
                              hipStream_t stream) {
  const float* x  = (const float*)d_in[0];
  const float* h1 = (const float*)d_in[1];
  const float* h2 = (const float*)d_in[2];
  auto P = [&](int i) { return (const float*)d_in[i]; };

  u16* xg0 = (u16*)d_ws;
  u16* xg1 = xg0 + (size_t)8192 * 1536;
  u16* outb = xg1 + (size_t)8192 * 1536;
  u16* hbuf = outb + (size_t)8192 * 1024;
  int* counters = (int*)(hbuf + 4 * 8192);
  float* out_f = (float*)d_out;
  float* out2 = out_f + 16;

  hipMemsetAsync(counters, 0, 8192 * sizeof(int), stream);

  // layer 0 (A = x fp32, K=2048)
  gemm_xg<1><<<dim3(64, 12, 2), 256, 0, stream>>>(x, P(3), P(7), P(5), P(9), xg0, xg1, 2048);
  gru_rec<<<dim3(4, 2), 512, 0, stream>>>(xg0, xg1, P(4), P(8), P(6), P(10),
                                          h1, h1 + 8192, outb, 1024, 0, hbuf, counters, T_SEQ);
  // layer 1 (A = outb bf16, K=1024)
  gemm_xg<0><<<dim3(64, 12, 2), 256, 0, stream>>>(outb, P(11), P(15), P(13), P(17), xg0, xg1, 1024);
  gru_rec<<<dim3(4, 2), 512, 0, stream>>>(xg0, xg1, P(12), P(16), P(14), P(18),
                                          h1 + 2 * 8192, h1 + 3 * 8192, outb, 1024, 0, hbuf,
                                          counters + 2048, T_SEQ);
  // layer 2 (K=1024)
  gemm_xg<0><<<dim3(64, 12, 2), 256, 0, stream>>>(outb, P(19), P(23), P(21), P(25), xg0, xg1, 1024);
  gru_rec<<<dim3(4, 2), 512, 0, stream>>>(xg0, xg1, P(20), P(24), P(22), P(26),
                                          h1 + 4 * 8192, h1 + 5 * 8192, outb, 1024, 0, hbuf,
                                          counters + 4096, T_SEQ);
  // g2 (unidirectional, K=1024) -> writes out2 region of d_out (fp32)
  gemm_xg<0><<<dim3(64, 12, 1), 256, 0, stream>>>(outb, P(27), P(27), P(29), P(29), xg0, xg1, 1024);
  gru_rec<<<dim3(4, 1), 512, 0, stream>>>(xg0, xg0, P(28), P(28), P(30), P(30),
                                          h2, h2, out2, 512, 1, hbuf, counters + 6144, T_SEQ);
  fc_kernel<<<16, 64, 0, stream>>>(out2, P(31), P(32), out_f);
}

// Round 7
// 20369.363 us; speedup vs baseline: 1.0487x; 1.0487x over previous
//
#include <hip/hip_runtime.h>
#include <cstdint>
#include <cstddef>

typedef unsigned short u16;
typedef unsigned int u32;
typedef unsigned long long u64;
typedef __attribute__((ext_vector_type(8))) short bf16x8;  // 8 bf16 (4 VGPRs) — MFMA A/B frag
typedef __attribute__((ext_vector_type(4))) float f32x4;   // MFMA C/D frag

#define T_SEQ 512
#define HID 512

// ---------- dtype helpers ----------
__device__ __forceinline__ u16 f2bf(float f) {
  union { float f; u32 i; } c; c.f = f;
  u32 r = (c.i + 0x7FFFu + ((c.i >> 16) & 1u)) >> 16;  // RNE
  return (u16)r;
}
__device__ __forceinline__ u16 f2h(float f) {
  union { _Float16 h; u16 u; } c; c.h = (_Float16)f; return c.u;
}
__device__ __forceinline__ float h2f(u16 u) {
  union { u16 u; _Float16 h; } c; c.u = u; return (float)c.h;
}
__device__ __forceinline__ float sigmf(float x) { return 1.f / (1.f + __expf(-x)); }
__device__ __forceinline__ float tanhfast(float x) {
  float e = __expf(2.f * x); return 1.f - 2.f / (e + 1.f);  // saturates to ±1
}
__device__ __forceinline__ bf16x8 pack8(const float* p) {
  float4 a = *(const float4*)(p);
  float4 b = *(const float4*)(p + 4);
  bf16x8 fr;
  fr[0] = (short)f2bf(a.x); fr[1] = (short)f2bf(a.y);
  fr[2] = (short)f2bf(a.z); fr[3] = (short)f2bf(a.w);
  fr[4] = (short)f2bf(b.x); fr[5] = (short)f2bf(b.y);
  fr[6] = (short)f2bf(b.z); fr[7] = (short)f2bf(b.w);
  return fr;
}

// ---------------------------------------------------------------------------
// xg GEMM: xg[dir][m][n] = sum_k A[m][k] * W[dir][n][k] + bias[dir][n]
// A: [8192, K] (fp32 if AF32 else bf16) row-major; W: [1536, K] fp32 row-major.
// out: fp16 [8192,1536]. 128x128 tile, BK=32, 4 waves (2x2), 4x4 16x16x32 MFMA.
// (unchanged — not the bottleneck)
// ---------------------------------------------------------------------------
template <int AF32>
__launch_bounds__(256)
__global__ void gemm_xg(const void* __restrict__ Av,
                        const float* __restrict__ W0, const float* __restrict__ W1,
                        const float* __restrict__ b0, const float* __restrict__ b1,
                        u16* __restrict__ xg0, u16* __restrict__ xg1, int K) {
  const int dir = blockIdx.z;
  const float* W = dir ? W1 : W0;
  const float* bias = dir ? b1 : b0;
  u16* xg = dir ? xg1 : xg0;
  const int bm = blockIdx.x, bn = blockIdx.y;
  const int tid = threadIdx.x, lane = tid & 63, wv = tid >> 6;
  const int wm = wv & 1, wn = wv >> 1, quad = lane >> 4, l15 = lane & 15;

  __shared__ u16 As[128 * 40];  // +8 pad per 32-elem row -> conflict-free b128 reads
  __shared__ u16 Bs[128 * 40];

  f32x4 acc[4][4] = {};
  const float* Wb = W + (size_t)(bn * 128) * K;

  for (int k0 = 0; k0 < K; k0 += 32) {
    __syncthreads();  // protect LDS from previous iter's readers
    if constexpr (AF32) {
      const float* Ab = (const float*)Av + (size_t)(bm * 128) * K;
#pragma unroll
      for (int it = 0; it < 4; ++it) {
        int c = tid + it * 256;  // 1024 float4 chunks
        int row = c >> 3, kp = (c & 7) * 4;
        float4 v = *(const float4*)(Ab + (size_t)row * K + k0 + kp);
        ushort4 s = { f2bf(v.x), f2bf(v.y), f2bf(v.z), f2bf(v.w) };
        *(ushort4*)(&As[row * 40 + kp]) = s;
      }
    } else {
      const u16* Ab = (const u16*)Av + (size_t)(bm * 128) * K;
#pragma unroll
      for (int it = 0; it < 2; ++it) {
        int c = tid + it * 256;  // 512 chunks of 8 bf16
        int row = c >> 2, kp = (c & 3) * 8;
        *(bf16x8*)(&As[row * 40 + kp]) = *(const bf16x8*)(Ab + (size_t)row * K + k0 + kp);
      }
    }
#pragma unroll
    for (int it = 0; it < 4; ++it) {  // W is always fp32
      int c = tid + it * 256;
      int row = c >> 3, kp = (c & 7) * 4;
      float4 v = *(const float4*)(Wb + (size_t)row * K + k0 + kp);
      ushort4 s = { f2bf(v.x), f2bf(v.y), f2bf(v.z), f2bf(v.w) };
      *(ushort4*)(&Bs[row * 40 + kp]) = s;
    }
    __syncthreads();
    bf16x8 af[4], bfv[4];
#pragma unroll
    for (int i = 0; i < 4; ++i) {
      af[i] = *(const bf16x8*)(&As[(wm * 64 + i * 16 + l15) * 40 + quad * 8]);
      bfv[i] = *(const bf16x8*)(&Bs[(wn * 64 + i * 16 + l15) * 40 + quad * 8]);
    }
#pragma unroll
    for (int mi = 0; mi < 4; ++mi)
#pragma unroll
      for (int ni = 0; ni < 4; ++ni)
        acc[mi][ni] = __builtin_amdgcn_mfma_f32_16x16x32_bf16(af[mi], bfv[ni], acc[mi][ni], 0, 0, 0);
  }

  // epilogue: + bias, store fp16
#pragma unroll
  for (int ni = 0; ni < 4; ++ni) {
    int n = bn * 128 + wn * 64 + ni * 16 + l15;
    float bv = bias[n];
#pragma unroll
    for (int mi = 0; mi < 4; ++mi) {
      int m0 = bm * 128 + wm * 64 + mi * 16 + quad * 4;
#pragma unroll
      for (int r = 0; r < 4; ++r)
        xg[(size_t)(m0 + r) * 1536 + n] = f2h(acc[mi][ni][r] + bv);
    }
  }
}

// ---------------------------------------------------------------------------
// Persistent GRU recurrence, v7: fence-free memory model (v5, proven correct)
// + best aggregation topology (v4).
//  * hbuf is accessed EXCLUSIVELY via agent-scope RELAXED atomics on BOTH
//    sides (stores when publishing, b64 loads when reading). These bypass
//    L1/L2 and operate at the MALL coherence point, so no cache can ever
//    hold an hbuf line -> NO acquire fence (buffer_inv) and NO release
//    (buffer_wbl2) anywhere in the step loop. (v6's nt loads were cacheable
//    -> intermittent stale L1/L2 hits -> post-timing divergence. v1-v4 all
//    paid per-step L2 sweep(s) from fence/release — the ~6µs/step floor.)
//  * Consumer: ALL waves poll the 4 per-WG flags (relaxed atomic loads,
//    s_sleep spin) — no rally barrier; each wave then loads its own A-frags
//    (32 coalesced atomic b64 loads, v5-verified pattern).
//  * Producer: publish h (relaxed atomic stores) -> explicit vmcnt(0) +
//    __syncthreads (all 8 waves' stores MALL-acked) -> tid0 RELAXED flag
//    store. One barrier per step, zero coherence sweeps.
//  * Sequence outputs: plain L2 stores AFTER the flag (off the critical
//    path; kernel-end implicit release flushes for the next dispatch).
// Safety: flag t+1 from WG X means all X's step-t reads (consumed by MFMA
// before publish, program order) and writes (vmcnt-drained at the barrier)
// retired -> overwriting parity t&1 at step t+1... skew bounded to 1 step;
// 2 parities suffice; flags monotone -> deadlock-free.
// ---------------------------------------------------------------------------
__launch_bounds__(512, 2)
__global__ void gru_rec(const u16* __restrict__ xg_f, const u16* __restrict__ xg_b,
                        const float* __restrict__ whh_f, const float* __restrict__ whh_b,
                        const float* __restrict__ bhh_f, const float* __restrict__ bhh_b,
                        const float* __restrict__ h0_f, const float* __restrict__ h0_b,
                        void* __restrict__ outp, int out_stride, int out_f32,
                        u16* __restrict__ hbuf, int* __restrict__ counters, int Tn) {
  const int dir = blockIdx.y;
  const u16* xg   = dir ? xg_b  : xg_f;
  const float* whh = dir ? whh_b : whh_f;
  const float* bhh = dir ? bhh_b : bhh_f;
  const float* h0  = dir ? h0_b  : h0_f;
  const int w = blockIdx.x;                      // 0..3
  const int tid = threadIdx.x, lane = tid & 63, wv = tid >> 6;  // wv 0..7
  const int quad = lane >> 4, l15 = lane & 15;
  const int gcol = w * 128 + wv * 16 + l15;      // hidden unit this lane owns
  int* flg = counters + dir * 1024;              // 4 per-WG flags, 64-int (256B) spaced
  u16* hb0 = hbuf + (dir * 2 + 0) * (16 * 512);
  u16* hb1 = hbuf + (dir * 2 + 1) * (16 * 512);
  const int dir_off = dir * 512;

  __shared__ u16 nlds[8 * 8192];                 // 128 KB: per-wave n-gate whh frags

  // --- whh B-frags: rows g*512+gcol, k = kt*32 + quad*8 + j (HW layout m89/m120) ---
  bf16x8 bfr[2][16];
  {
    const float* wr = whh + (size_t)(0 * 512 + gcol) * 512 + quad * 8;
    const float* wz = whh + (size_t)(1 * 512 + gcol) * 512 + quad * 8;
    const float* wn = whh + (size_t)(2 * 512 + gcol) * 512 + quad * 8;
#pragma unroll
    for (int kt = 0; kt < 16; ++kt) {
      bfr[0][kt] = pack8(wr + kt * 32);
      bfr[1][kt] = pack8(wz + kt * 32);
      *(bf16x8*)(&nlds[wv * 8192 + kt * 512 + lane * 8]) = pack8(wn + kt * 32);  // wave-private
    }
  }
  const float bh0 = bhh[0 * 512 + gcol];
  const float bh1 = bhh[1 * 512 + gcol];
  const float bh2 = bhh[2 * 512 + gcol];

  // --- init h: fp32 regs (exact carry) + publish bf16 h0 slice to hb1 ---
  float hv[4];
#pragma unroll
  for (int r = 0; r < 4; ++r) hv[r] = h0[(quad * 4 + r) * 512 + gcol];
#pragma unroll
  for (int r = 0; r < 4; ++r) {
    u32 hb = (u32)f2bf(hv[r]);
    u32 pb = (u32)__shfl_xor((int)hb, 1, 64);
    if (!(lane & 1))
      __hip_atomic_store((u32*)(hb1 + (quad * 4 + r) * 512 + gcol), hb | (pb << 16),
                         __ATOMIC_RELAXED, __HIP_MEMORY_SCOPE_AGENT);
  }
  asm volatile("s_waitcnt vmcnt(0)" ::: "memory");  // h0 stores MALL-acked
  __syncthreads();                                  // all 8 waves drained
  if (tid == 0)
    __hip_atomic_store(&flg[w * 64], 1, __ATOMIC_RELAXED, __HIP_MEMORY_SCOPE_AGENT);

  for (int t = 0; t < Tn; ++t) {
    const int te = dir ? (Tn - 1 - t) : t;

    // (a) xg slice for this lane's 4 batch rows -> 12 regs (completes under poll)
    u16 xv[12];
    {
      const u16* xb = xg + (size_t)te * 1536 + gcol;
#pragma unroll
      for (int r = 0; r < 4; ++r)
#pragma unroll
        for (int g = 0; g < 3; ++g)
          xv[r * 3 + g] = xb[(size_t)(quad * 4 + r) * Tn * 1536 + g * 512];
    }

    // (b) every wave polls the 4 per-WG flags (relaxed atomics; no fence,
    //     no rally barrier) — fully self-timed
    {
      const int target = t + 1;
      while (1) {
        int v = (lane < 4)
            ? __hip_atomic_load(&flg[lane * 64], __ATOMIC_RELAXED, __HIP_MEMORY_SCOPE_AGENT)
            : 0x7fffffff;
        if (__all(v >= target)) break;
        __builtin_amdgcn_s_sleep(1);
      }
    }

    // (c) A-frags: full 16x512 bf16 h via coalesced relaxed-atomic b64 loads
    //     (MALL-direct; fresh by construction — v5-verified access pattern)
    const u64* hq = (const u64*)(((t & 1) ? hb0 : hb1) + l15 * 512 + quad * 8);
    bf16x8 afr[16];
#pragma unroll
    for (int kt = 0; kt < 16; ++kt) {
      u64 lo = __hip_atomic_load(hq + kt * 8,     __ATOMIC_RELAXED, __HIP_MEMORY_SCOPE_AGENT);
      u64 hi = __hip_atomic_load(hq + kt * 8 + 1, __ATOMIC_RELAXED, __HIP_MEMORY_SCOPE_AGENT);
      union { bf16x8 v; u64 q[2]; } uu;
      uu.q[0] = lo; uu.q[1] = hi;
      afr[kt] = uu.v;
    }

    // (d) MFMA: three independent 16-deep chains (r,z from regs; n from LDS)
    f32x4 accr = {0.f, 0.f, 0.f, 0.f}, accz = accr, accn = accr;
#pragma unroll
    for (int kt = 0; kt < 16; ++kt) {
      bf16x8 nf = *(const bf16x8*)(&nlds[wv * 8192 + kt * 512 + lane * 8]);
      accr = __builtin_amdgcn_mfma_f32_16x16x32_bf16(afr[kt], bfr[0][kt], accr, 0, 0, 0);
      accz = __builtin_amdgcn_mfma_f32_16x16x32_bf16(afr[kt], bfr[1][kt], accz, 0, 0, 0);
      accn = __builtin_amdgcn_mfma_f32_16x16x32_bf16(afr[kt], nf, accn, 0, 0, 0);
    }

    // (e) lane-local gate combine + fp32 h update
#pragma unroll
    for (int r = 0; r < 4; ++r) {
      float xr = h2f(xv[r * 3 + 0]);
      float xz = h2f(xv[r * 3 + 1]);
      float xn = h2f(xv[r * 3 + 2]);
      float rg = sigmf(xr + accr[r] + bh0);
      float zg = sigmf(xz + accz[r] + bh1);
      float ng = tanhfast(xn + rg * (accn[r] + bh2));
      hv[r] = (1.f - zg) * ng + zg * hv[r];
    }

    // (f) publish bf16 h (packed pairs via shfl; relaxed agent atomic stores)
    u16* hbw = (t & 1) ? hb1 : hb0;
    u32 opk[4];
#pragma unroll
    for (int r = 0; r < 4; ++r) {
      u32 hb = (u32)f2bf(hv[r]);
      u32 pb = (u32)__shfl_xor((int)hb, 1, 64);
      opk[r] = hb | (pb << 16);
      if (!(lane & 1))
        __hip_atomic_store((u32*)(hbw + (quad * 4 + r) * 512 + gcol), opk[r],
                           __ATOMIC_RELAXED, __HIP_MEMORY_SCOPE_AGENT);
    }
    // (g) arrival: explicit MALL-ack drain + barrier (aggregates all 8 waves)
    //     + ONE relaxed flag store — no coherence sweeps anywhere
    asm volatile("s_waitcnt vmcnt(0)" ::: "memory");
    __syncthreads();
    if (tid == 0)
      __hip_atomic_store(&flg[w * 64], t + 2, __ATOMIC_RELAXED, __HIP_MEMORY_SCOPE_AGENT);

    // (h) sequence output — plain L2-buffered stores AFTER the flag
    if (out_f32) {
#pragma unroll
      for (int r = 0; r < 4; ++r) {
        float pf = __shfl_xor(hv[r], 1, 64);
        if (!(lane & 1)) {
          float2 o = { hv[r], pf };
          *(float2*)((float*)outp + (size_t)((quad * 4 + r) * Tn + te) * out_stride + dir_off + gcol) = o;
        }
      }
    } else {
#pragma unroll
      for (int r = 0; r < 4; ++r)
        if (!(lane & 1))
          *(u32*)((u16*)outp + (size_t)((quad * 4 + r) * Tn + te) * out_stride + dir_off + gcol) = opk[r];
    }
  }
}

// ---------------------------------------------------------------------------
// Final FC: d_out[b] = sigmoid(out2[b, T-1, :] . fc_w + fc_b)   (all fp32)
// ---------------------------------------------------------------------------
__global__ void fc_kernel(const float* __restrict__ out2, const float* __restrict__ fc_w,
                          const float* __restrict__ fc_b, float* __restrict__ dst) {
  int b = blockIdx.x, lane = threadIdx.x;  // 64 threads
  const float* row = out2 + ((size_t)b * T_SEQ + (T_SEQ - 1)) * HID;
  float s = 0.f;
  for (int j = lane; j < HID; j += 64) s += row[j] * fc_w[j];
#pragma unroll
  for (int off = 32; off > 0; off >>= 1) s += __shfl_down(s, off, 64);
  if (lane == 0) dst[b] = sigmf(s + fc_b[0]);
}

// ---------------------------------------------------------------------------
// inputs (fp32): 0 x, 1 h1, 2 h2, [3..6]=l0f(wih,whh,bih,bhh), [7..10]=l0b,
// [11..14]=l1f, [15..18]=l1b, [19..22]=l2f, [23..26]=l2b, [27..30]=g2, 31 fc_w, 32 fc_b
// d_out (fp32): 16 sigmoid logits, then out2 [16,512,512].
// ws: xg0 fp16 (8192*1536) | xg1 fp16 | outb bf16 (8192*1024) | hbuf bf16 (4*8192)
//     | counters (8192 int)
// ---------------------------------------------------------------------------
extern "C" void kernel_launch(void* const* d_in, const int* in_sizes, int n_in,
                              void* d_out, int out_size, void* d_ws, size_t ws_size,
                              hipStream_t stream) {
  const float* x  = (const float*)d_in[0];
  const float* h1 = (const float*)d_in[1];
  const float* h2 = (const float*)d_in[2];
  auto P = [&](int i) { return (const float*)d_in[i]; };

  u16* xg0 = (u16*)d_ws;
  u16* xg1 = xg0 + (size_t)8192 * 1536;
  u16* outb = xg1 + (size_t)8192 * 1536;
  u16* hbuf = outb + (size_t)8192 * 1024;
  int* counters = (int*)(hbuf + 4 * 8192);
  float* out_f = (float*)d_out;
  float* out2 = out_f + 16;

  hipMemsetAsync(counters, 0, 8192 * sizeof(int), stream);

  // layer 0 (A = x fp32, K=2048)
  gemm_xg<1><<<dim3(64, 12, 2), 256, 0, stream>>>(x, P(3), P(7), P(5), P(9), xg0, xg1, 2048);
  gru_rec<<<dim3(4, 2), 512, 0, stream>>>(xg0, xg1, P(4), P(8), P(6), P(10),
                                          h1, h1 + 8192, outb, 1024, 0, hbuf, counters, T_SEQ);
  // layer 1 (A = outb bf16, K=1024)
  gemm_xg<0><<<dim3(64, 12, 2), 256, 0, stream>>>(outb, P(11), P(15), P(13), P(17), xg0, xg1, 1024);
  gru_rec<<<dim3(4, 2), 512, 0, stream>>>(xg0, xg1, P(12), P(16), P(14), P(18),
                                          h1 + 2 * 8192, h1 + 3 * 8192, outb, 1024, 0, hbuf,
                                          counters + 2048, T_SEQ);
  // layer 2 (K=1024)
  gemm_xg<0><<<dim3(64, 12, 2), 256, 0, stream>>>(outb, P(19), P(23), P(21), P(25), xg0, xg1, 1024);
  gru_rec<<<dim3(4, 2), 512, 0, stream>>>(xg0, xg1, P(20), P(24), P(22), P(26),
                                          h1 + 4 * 8192, h1 + 5 * 8192, outb, 1024, 0, hbuf,
                                          counters + 4096, T_SEQ);
  // g2 (unidirectional, K=1024) -> writes out2 region of d_out (fp32)
  gemm_xg<0><<<dim3(64, 12, 1), 256, 0, stream>>>(outb, P(27), P(27), P(29), P(29), xg0, xg1, 1024);
  gru_rec<<<dim3(4, 1), 512, 0, stream>>>(xg0, xg0, P(28), P(28), P(30), P(30),
                                          h2, h2, out2, 512, 1, hbuf, counters + 6144, T_SEQ);
  fc_kernel<<<16, 64, 0, stream>>>(out2, P(31), P(32), out_f);
}